// Round 8
// baseline (200.826 us; speedup 1.0000x reference)
//
#include <hip/hip_runtime.h>
#include <hip/hip_fp16.h>

#define SQRT3 1.7320508075688772f
#define INV_SQRT3 0.5773502691896258f
#define CAP 64

#define WAVE_SYNC() do { asm volatile("s_waitcnt lgkmcnt(0)" ::: "memory"); \
                         __builtin_amdgcn_wave_barrier(); } while (0)

// ---------------- fused build: scatter (first) + prep ----------------
// scatter: p = atomicAdd(&cnt[d],1); csrP[d*CAP+p] = (u16)s. cnt[d] ends as degree.
// prep: featH[node*32+cl] = half4{s_cl, v_cl0, v_cl1, v_cl2}; pos4; TRANSPOSED folded W:
//   WST[j*64+u]: u<32 -> 0.125*w0[u]*Ws[u][j];  u>=32 -> 0.125*w3[u']*inv_sqrt3*Ws[u][j]
//   WVT[o*64+u]: u<32 -> 0.125*w1[u]*Wv[u][o];  u>=32 -> 0.125*w2[u']*Wv[u][o]
template<typename IDX>
__global__ void build_kernel(const int* __restrict__ esrc, const int* __restrict__ edst,
                             const float* __restrict__ feat, const float* __restrict__ pos,
                             const float* __restrict__ Ws, const float* __restrict__ Wv,
                             const float* __restrict__ tpw,
                             int* __restrict__ cnt, IDX* __restrict__ csrP,
                             uint2* __restrict__ featH, float4* __restrict__ pos4,
                             float* __restrict__ WST, float* __restrict__ WVT,
                             int N, int E, int sblocks) {
    int b = blockIdx.x;
    if (b < sblocks) {                     // ---- scatter part ----
        int t = b * blockDim.x + threadIdx.x;
        int e0 = t * 4;
        if (e0 + 4 <= E) {
            int4 s4 = *(const int4*)(esrc + e0);
            int4 d4 = *(const int4*)(edst + e0);
            int p;
            p = atomicAdd(&cnt[d4.x], 1); if (p < CAP) csrP[(size_t)d4.x * CAP + p] = (IDX)s4.x;
            p = atomicAdd(&cnt[d4.y], 1); if (p < CAP) csrP[(size_t)d4.y * CAP + p] = (IDX)s4.y;
            p = atomicAdd(&cnt[d4.z], 1); if (p < CAP) csrP[(size_t)d4.z * CAP + p] = (IDX)s4.z;
            p = atomicAdd(&cnt[d4.w], 1); if (p < CAP) csrP[(size_t)d4.w * CAP + p] = (IDX)s4.w;
        } else {
            for (int e = e0; e < E; ++e) {
                int d = edst[e];
                int p = atomicAdd(&cnt[d], 1);
                if (p < CAP) csrP[(size_t)d * CAP + p] = (IDX)esrc[e];
            }
        }
        return;
    }
    // ---- prep part ----
    int i = (b - sblocks) * blockDim.x + threadIdx.x;
    int totalF = N * 32;
    if (i < totalF) {
        int node = i >> 5, cl = i & 31;
        const float* fb = feat + (size_t)node * 128;
        float s  = fb[cl];
        float v0 = fb[32 + 3 * cl], v1 = fb[33 + 3 * cl], v2 = fb[34 + 3 * cl];
        __half2 h0 = __floats2half2_rn(s, v0);
        __half2 h1 = __floats2half2_rn(v1, v2);
        uint2 r;
        r.x = *(const unsigned int*)&h0;
        r.y = *(const unsigned int*)&h1;
        featH[i] = r;
        return;
    }
    int j = i - totalF;
    if (j < N) {
        pos4[j] = make_float4(pos[3 * j], pos[3 * j + 1], pos[3 * j + 2], 0.f);
        return;
    }
    int k = j - N;
    if (k < 2048) {
        int u = k >> 5, c = k & 31;        // c = output column (j for s, o for v)
        float ws = Ws[k], wv = Wv[k];
        float fs, fv;
        if (u < 32) {
            fs = 0.125f * tpw[u] * ws;
            fv = 0.125f * tpw[32 + u] * wv;
        } else {
            int uu = u - 32;
            fs = 0.125f * tpw[96 + uu] * INV_SQRT3 * ws;
            fv = 0.125f * tpw[64 + uu] * wv;
        }
        WST[c * 64 + u] = fs;
        WVT[c * 64 + u] = fv;
    }
}

// ---------------- per-node gather + TP + linear ----------------
// 1 wave/node, QUARTER-wave per edge: lane owns channels {2cq, 2cq+1} and reads
// one uint4 (8 f16 = both channels' {s,v0,v1,v2}) per edge -> 16B coalesced loads.
// Per 4-edge body per lane: 1 ds_read_b128 + 1 global uint4 + ~28 VALU.

template<typename IDX>
__global__ __launch_bounds__(256) void node_kernel(
    const uint4* __restrict__ featH4, const float4* __restrict__ pos4,
    const IDX* __restrict__ csrP, const int* __restrict__ cnt,
    const float* __restrict__ WST, const float* __restrict__ WVT,
    float* __restrict__ out, int N)
{
    __shared__ float4 geom[4][64];
    __shared__ float  sS[4][68], sX[4][68], sY[4][68], sZ[4][68];
    int lane = threadIdx.x & 63;
    int w    = threadIdx.x >> 6;
    int node = blockIdx.x * 4 + w;
    if (node >= N) return;                 // whole-wave exit; no block barriers used

    int deg = cnt[node];                   // cursor after scatter == degree
    int len = deg < CAP ? deg : CAP;
    int qw = lane >> 4;                    // quarter 0..3
    int cq = lane & 15;                    // channel pair id

    float4 pd = pos4[node];                // wave-uniform

    if (lane < len) {
        int s = (int)csrP[(size_t)node * CAP + lane];
        float4 ps = pos4[s];
        float ex = pd.x - ps.x, ey = pd.y - ps.y, ez = pd.z - ps.z;
        float rr = SQRT3 * rsqrtf(ex * ex + ey * ey + ez * ez + 1e-12f);
        geom[w][lane] = make_float4(rr * ex, rr * ey, rr * ez, __int_as_float(s));
    }
    WAVE_SYNC();

    // accumulators: channel a = 2cq, channel b = 2cq+1
    float A0a = 0.f, A1xa = 0.f, A1ya = 0.f, A1za = 0.f;
    float V0a = 0.f, V1a = 0.f, V2a = 0.f, T3a = 0.f;
    float A0b = 0.f, A1xb = 0.f, A1yb = 0.f, A1zb = 0.f;
    float V0b = 0.f, V1b = 0.f, V2b = 0.f, T3b = 0.f;

    int even4 = len & ~3;
    #pragma unroll 2
    for (int m = 0; m < even4; m += 4) {
        float4 g = geom[w][m + qw];
        int si = __float_as_int(g.w);
        uint4 fr = featH4[(size_t)si * 16 + cq];
        float2 l0 = __half22float2(*(const __half2*)&fr.x);   // {s_a, va0}
        float2 l1 = __half22float2(*(const __half2*)&fr.y);   // {va1, va2}
        float2 l2 = __half22float2(*(const __half2*)&fr.z);   // {s_b, vb0}
        float2 l3 = __half22float2(*(const __half2*)&fr.w);   // {vb1, vb2}
        A0a += l0.x;
        A1xa = fmaf(l0.x, g.x, A1xa); A1ya = fmaf(l0.x, g.y, A1ya); A1za = fmaf(l0.x, g.z, A1za);
        V0a += l0.y; V1a += l1.x; V2a += l1.y;
        T3a = fmaf(l0.y, g.x, fmaf(l1.x, g.y, fmaf(l1.y, g.z, T3a)));
        A0b += l2.x;
        A1xb = fmaf(l2.x, g.x, A1xb); A1yb = fmaf(l2.x, g.y, A1yb); A1zb = fmaf(l2.x, g.z, A1zb);
        V0b += l2.y; V1b += l3.x; V2b += l3.y;
        T3b = fmaf(l2.y, g.x, fmaf(l3.x, g.y, fmaf(l3.y, g.z, T3b)));
    }
    int rem = len - even4;
    if (rem) {                             // tail: quarters qw < rem participate
        bool ok = qw < rem;
        float4 g = geom[w][even4 + qw];    // in-bounds (even4 <= 60 when rem > 0)
        int si = ok ? __float_as_int(g.w) : 0;
        uint4 fr = featH4[(size_t)si * 16 + cq];
        if (ok) {
            float2 l0 = __half22float2(*(const __half2*)&fr.x);
            float2 l1 = __half22float2(*(const __half2*)&fr.y);
            float2 l2 = __half22float2(*(const __half2*)&fr.z);
            float2 l3 = __half22float2(*(const __half2*)&fr.w);
            A0a += l0.x;
            A1xa = fmaf(l0.x, g.x, A1xa); A1ya = fmaf(l0.x, g.y, A1ya); A1za = fmaf(l0.x, g.z, A1za);
            V0a += l0.y; V1a += l1.x; V2a += l1.y;
            T3a = fmaf(l0.y, g.x, fmaf(l1.x, g.y, fmaf(l1.y, g.z, T3a)));
            A0b += l2.x;
            A1xb = fmaf(l2.x, g.x, A1xb); A1yb = fmaf(l2.x, g.y, A1yb); A1zb = fmaf(l2.x, g.z, A1zb);
            V0b += l2.y; V1b += l3.x; V2b += l3.y;
            T3b = fmaf(l2.y, g.x, fmaf(l3.x, g.y, fmaf(l3.y, g.z, T3b)));
        }
    }

    // cross-quarter reduce (quarters hold same channels over disjoint edge subsets)
#define RED2(v) do { v += __shfl_xor(v, 16); v += __shfl_xor(v, 32); } while (0)
    RED2(A0a); RED2(A1xa); RED2(A1ya); RED2(A1za);
    RED2(V0a); RED2(V1a);  RED2(V2a);  RED2(T3a);
    RED2(A0b); RED2(A1xb); RED2(A1yb); RED2(A1zb);
    RED2(V0b); RED2(V1b);  RED2(V2b);  RED2(T3b);
#undef RED2

    // SoA aggregate: [0,32)=s-path raw {A0 | A1x/y/z}, [32,64)=v-path raw {T3 | V0/1/2}
    if (qw == 0) {
        *(float2*)&sS[w][2 * cq] = make_float2(A0a, A0b);
        *(float2*)&sX[w][2 * cq] = make_float2(A1xa, A1xb);
        *(float2*)&sY[w][2 * cq] = make_float2(A1ya, A1yb);
        *(float2*)&sZ[w][2 * cq] = make_float2(A1za, A1zb);
    } else if (qw == 1) {
        *(float2*)&sS[w][32 + 2 * cq] = make_float2(T3a, T3b);
        *(float2*)&sX[w][32 + 2 * cq] = make_float2(V0a, V0b);
        *(float2*)&sY[w][32 + 2 * cq] = make_float2(V1a, V1b);
        *(float2*)&sZ[w][32 + 2 * cq] = make_float2(V2a, V2b);
    }
    WAVE_SYNC();

    // epilogue: outputs j = lane, lane+64; contiguous transposed weight rows (float4)
    size_t ob = (size_t)node * 128;
    #pragma unroll
    for (int t = 0; t < 2; ++t) {
        int j = lane + 64 * t;
        const float *ap, *wp;
        if (j < 32) {
            ap = sS[w]; wp = WST + j * 64;
        } else {
            int v = j - 32;
            int o = v / 3, mm = v - 3 * o;
            ap = (mm == 0) ? sX[w] : (mm == 1) ? sY[w] : sZ[w];
            wp = WVT + o * 64;
        }
        float r = 0.f;
        #pragma unroll
        for (int q = 0; q < 16; ++q) {
            float4 a = *(const float4*)(ap + 4 * q);
            float4 b = *(const float4*)(wp + 4 * q);
            r = fmaf(a.x, b.x, r); r = fmaf(a.y, b.y, r);
            r = fmaf(a.z, b.z, r); r = fmaf(a.w, b.w, r);
        }
        out[ob + j] = r;                   // all scales folded into WST/WVT
    }
}

extern "C" void kernel_launch(void* const* d_in, const int* in_sizes, int n_in,
                              void* d_out, int out_size, void* d_ws, size_t ws_size,
                              hipStream_t stream) {
    const float* feat = (const float*)d_in[0];
    const float* pos  = (const float*)d_in[1];
    const int*   esrc = (const int*)d_in[2];
    const int*   edst = (const int*)d_in[3];
    const float* tpw  = (const float*)d_in[4];
    const float* Ws   = (const float*)d_in[5];
    const float* Wv   = (const float*)d_in[6];
    float* out = (float*)d_out;

    int N = in_sizes[0] / 128;
    int E = in_sizes[2];

    uint2*  featH = (uint2*)d_ws;                        // N*32 entries (12.8 MB)
    float4* pos4  = (float4*)(featH + (size_t)N * 32);   // N (0.8 MB)
    unsigned short* csrU = (unsigned short*)(pos4 + N);  // N*CAP u16 (6.4 MB)
    int*    cnt   = (int*)(csrU + (size_t)N * CAP);      // N
    float*  WST   = (float*)(cnt + N);                   // 2048
    float*  WVT   = WST + 2048;                          // 2048

    hipMemsetAsync(cnt, 0, (size_t)N * sizeof(int), stream);

    const int tb = 256;
    int sblocks = (E / 4 + tb - 1) / tb;
    int prepTot = N * 32 + N + 2048;
    int pblocks = (prepTot + tb - 1) / tb;
    int nblocks = (N + 3) / 4;

    if (N <= 65535) {
        build_kernel<unsigned short><<<sblocks + pblocks, tb, 0, stream>>>(
            esrc, edst, feat, pos, Ws, Wv, tpw, cnt, csrU, featH, pos4, WST, WVT, N, E, sblocks);
        node_kernel<unsigned short><<<nblocks, 256, 0, stream>>>(
            (const uint4*)featH, pos4, csrU, cnt, WST, WVT, out, N);
    } else {
        int* csrI = (int*)csrU;            // falls back to int CSR (layout still fits typical ws)
        build_kernel<int><<<sblocks + pblocks, tb, 0, stream>>>(
            esrc, edst, feat, pos, Ws, Wv, tpw, cnt, csrI, featH, pos4, WST, WVT, N, E, sblocks);
        node_kernel<int><<<nblocks, 256, 0, stream>>>(
            (const uint4*)featH, pos4, csrI, cnt, WST, WVT, out, N);
    }
}

// Round 9
// 196.427 us; speedup vs baseline: 1.0224x; 1.0224x over previous
//
#include <hip/hip_runtime.h>
#include <hip/hip_fp16.h>

#define SQRT3 1.7320508075688772f
#define INV_SQRT3 0.5773502691896258f
#define CAP 64

#define WAVE_SYNC() do { asm volatile("s_waitcnt lgkmcnt(0)" ::: "memory"); \
                         __builtin_amdgcn_wave_barrier(); } while (0)

// ---------------- fused prep: featH(f16) + pos4 + folded transposed weights + cnt=0 ----
// featH[node*32+cl] = half4{s_cl, v_cl0, v_cl1, v_cl2}
// WST[j*64+u]: u<32 -> 0.125*w0[u]*Ws[u][j]; u>=32 -> 0.125*w3[u']*inv_sqrt3*Ws[u][j]
// WVT[o*64+u]: u<32 -> 0.125*w1[u]*Wv[u][o]; u>=32 -> 0.125*w2[u']*Wv[u][o]
__global__ void prep_kernel(const float* __restrict__ feat, const float* __restrict__ pos,
                            const float* __restrict__ Ws, const float* __restrict__ Wv,
                            const float* __restrict__ tpw,
                            uint2* __restrict__ featH, float4* __restrict__ pos4,
                            int* __restrict__ cnt,
                            float* __restrict__ WST, float* __restrict__ WVT, int N) {
    int i = blockIdx.x * blockDim.x + threadIdx.x;
    int totalF = N * 32;
    if (i < totalF) {
        int node = i >> 5, cl = i & 31;
        const float* fb = feat + (size_t)node * 128;
        float s  = fb[cl];
        float v0 = fb[32 + 3 * cl], v1 = fb[33 + 3 * cl], v2 = fb[34 + 3 * cl];
        __half2 h0 = __floats2half2_rn(s, v0);
        __half2 h1 = __floats2half2_rn(v1, v2);
        uint2 r;
        r.x = *(const unsigned int*)&h0;
        r.y = *(const unsigned int*)&h1;
        featH[i] = r;
        return;
    }
    int j = i - totalF;
    if (j < N) {
        pos4[j] = make_float4(pos[3 * j], pos[3 * j + 1], pos[3 * j + 2], 0.f);
        cnt[j] = 0;                        // zero scatter cursors (no memset pass)
        return;
    }
    int k = j - N;
    if (k < 2048) {
        int u = k >> 5, c = k & 31;        // c = output column (j for s-path, o for v-path)
        float ws = Ws[k], wv = Wv[k];
        float fs, fv;
        if (u < 32) {
            fs = 0.125f * tpw[u] * ws;
            fv = 0.125f * tpw[32 + u] * wv;
        } else {
            int uu = u - 32;
            fs = 0.125f * tpw[96 + uu] * INV_SQRT3 * ws;
            fv = 0.125f * tpw[64 + uu] * wv;
        }
        WST[c * 64 + u] = fs;
        WVT[c * 64 + u] = fv;
    }
}

// ---------------- single-pass padded-CSR scatter ----------------
// p = atomicAdd(cursor); csrP[d*CAP+p] = s.  Afterwards cnt[d] == degree(d).
// (Poisson(16) degrees: P(deg > 64) negligible; guard drops overflow slots.)

__global__ void scatter_kernel(const int* __restrict__ esrc, const int* __restrict__ edst,
                               int* __restrict__ cnt, int* __restrict__ csrP, int E) {
    int t = blockIdx.x * blockDim.x + threadIdx.x;
    int e0 = t * 4;
    if (e0 + 4 <= E) {
        int4 s4 = *(const int4*)(esrc + e0);
        int4 d4 = *(const int4*)(edst + e0);
        int p;
        p = atomicAdd(&cnt[d4.x], 1); if (p < CAP) csrP[(size_t)d4.x * CAP + p] = s4.x;
        p = atomicAdd(&cnt[d4.y], 1); if (p < CAP) csrP[(size_t)d4.y * CAP + p] = s4.y;
        p = atomicAdd(&cnt[d4.z], 1); if (p < CAP) csrP[(size_t)d4.z * CAP + p] = s4.z;
        p = atomicAdd(&cnt[d4.w], 1); if (p < CAP) csrP[(size_t)d4.w * CAP + p] = s4.w;
    } else {
        for (int e = e0; e < E; ++e) {
            int d = edst[e];
            int p = atomicAdd(&cnt[d], 1);
            if (p < CAP) csrP[(size_t)d * CAP + p] = esrc[e];
        }
    }
}

// ---------------- per-node gather + TP + linear ----------------
// 1 wave/node, HALF-wave per edge, lane owns channel cl = {s,v0,v1,v2} (f16x4, 8B load).
// csrL (b32) split from geom (b128): feat address chain = ds_read_b32 -> global_load;
// geometry b128 read overlaps gather latency. unroll 8 -> up to 8 gathers in flight.

__global__ __launch_bounds__(256) void node_kernel(
    const uint2* __restrict__ featH, const float4* __restrict__ pos4,
    const int* __restrict__ csrP, const int* __restrict__ cnt,
    const float* __restrict__ WST, const float* __restrict__ WVT,
    float* __restrict__ out, int N)
{
    __shared__ int    csrL[4][64];
    __shared__ float4 geom[4][64];
    __shared__ float  sS[4][68], sX[4][68], sY[4][68], sZ[4][68];
    int lane = threadIdx.x & 63;
    int w    = threadIdx.x >> 6;
    int node = blockIdx.x * 4 + w;
    if (node >= N) return;                 // whole-wave exit; no block barriers used

    int deg = cnt[node];                   // cursor after scatter == degree
    int len = deg < CAP ? deg : CAP;
    int half = lane >> 5;
    int cl   = lane & 31;

    float4 pd = pos4[node];                // wave-uniform

    if (lane < len) {
        int s = csrP[(size_t)node * CAP + lane];
        csrL[w][lane] = s;
        float4 ps = pos4[s];
        float ex = pd.x - ps.x, ey = pd.y - ps.y, ez = pd.z - ps.z;
        float rr = SQRT3 * rsqrtf(ex * ex + ey * ey + ez * ez + 1e-12f);
        geom[w][lane] = make_float4(rr * ex, rr * ey, rr * ez, 0.f);
    }
    WAVE_SYNC();

    float A0 = 0.f, A1x = 0.f, A1y = 0.f, A1z = 0.f;   // s-channel cl: a0, a1
    float V0 = 0.f, V1 = 0.f, V2 = 0.f, T3 = 0.f;      // v-channel cl: a2, a3(raw)

    #pragma unroll 8
    for (int m = 0; m + 2 <= len; m += 2) {
        int e  = m + half;
        int si = csrL[w][e];
        uint2 fr = featH[(size_t)si * 32 + cl];
        float4 g = geom[w][e];
        float2 lo = __half22float2(*(const __half2*)&fr.x);   // {s, v0}
        float2 hi = __half22float2(*(const __half2*)&fr.y);   // {v1, v2}
        A0 += lo.x;
        A1x = fmaf(lo.x, g.x, A1x); A1y = fmaf(lo.x, g.y, A1y); A1z = fmaf(lo.x, g.z, A1z);
        V0 += lo.y; V1 += hi.x; V2 += hi.y;
        T3 = fmaf(lo.y, g.x, fmaf(hi.x, g.y, fmaf(hi.y, g.z, T3)));
    }
    if (len & 1) {                         // odd tail: half 0 only
        if (half == 0) {
            int si = csrL[w][len - 1];
            uint2 fr = featH[(size_t)si * 32 + cl];
            float4 g = geom[w][len - 1];
            float2 lo = __half22float2(*(const __half2*)&fr.x);
            float2 hi = __half22float2(*(const __half2*)&fr.y);
            A0 += lo.x;
            A1x = fmaf(lo.x, g.x, A1x); A1y = fmaf(lo.x, g.y, A1y); A1z = fmaf(lo.x, g.z, A1z);
            V0 += lo.y; V1 += hi.x; V2 += hi.y;
            T3 = fmaf(lo.y, g.x, fmaf(hi.x, g.y, fmaf(hi.y, g.z, T3)));
        }
    }

    // cross-half reduce (lanes L, L+32 hold same channel over disjoint edges)
    A0 += __shfl_xor(A0, 32);  A1x += __shfl_xor(A1x, 32);
    A1y += __shfl_xor(A1y, 32); A1z += __shfl_xor(A1z, 32);
    V0 += __shfl_xor(V0, 32);  V1 += __shfl_xor(V1, 32);
    V2 += __shfl_xor(V2, 32);  T3 += __shfl_xor(T3, 32);

    // SoA aggregate: [0,32)=s-path raw {A0 | A1x/y/z}, [32,64)=v-path raw {T3 | V0/1/2}
    int k = half ? (32 + cl) : cl;
    sS[w][k] = half ? T3 : A0;
    sX[w][k] = half ? V0 : A1x;
    sY[w][k] = half ? V1 : A1y;
    sZ[w][k] = half ? V2 : A1z;
    WAVE_SYNC();

    // epilogue: outputs j = lane, lane+64; contiguous transposed weight rows (float4)
    size_t ob = (size_t)node * 128;
    #pragma unroll
    for (int t = 0; t < 2; ++t) {
        int j = lane + 64 * t;
        const float *ap, *wp;
        if (j < 32) {
            ap = sS[w]; wp = WST + j * 64;
        } else {
            int v = j - 32;
            int o = v / 3, mm = v - 3 * o;
            ap = (mm == 0) ? sX[w] : (mm == 1) ? sY[w] : sZ[w];
            wp = WVT + o * 64;
        }
        float r = 0.f;
        #pragma unroll
        for (int q = 0; q < 16; ++q) {
            float4 a = *(const float4*)(ap + 4 * q);
            float4 b = *(const float4*)(wp + 4 * q);
            r = fmaf(a.x, b.x, r); r = fmaf(a.y, b.y, r);
            r = fmaf(a.z, b.z, r); r = fmaf(a.w, b.w, r);
        }
        out[ob + j] = r;                   // all scales folded into WST/WVT
    }
}

extern "C" void kernel_launch(void* const* d_in, const int* in_sizes, int n_in,
                              void* d_out, int out_size, void* d_ws, size_t ws_size,
                              hipStream_t stream) {
    const float* feat = (const float*)d_in[0];
    const float* pos  = (const float*)d_in[1];
    const int*   esrc = (const int*)d_in[2];
    const int*   edst = (const int*)d_in[3];
    const float* tpw  = (const float*)d_in[4];
    const float* Ws   = (const float*)d_in[5];
    const float* Wv   = (const float*)d_in[6];
    float* out = (float*)d_out;

    int N = in_sizes[0] / 128;
    int E = in_sizes[2];

    uint2*  featH = (uint2*)d_ws;                      // N*32   (12.8 MB)
    float4* pos4  = (float4*)(featH + (size_t)N * 32); // N      (0.8 MB)
    int*    csrP  = (int*)(pos4 + N);                  // N*CAP  (12.8 MB)
    int*    cnt   = csrP + (size_t)N * CAP;            // N      (0.2 MB)
    float*  WST   = (float*)(cnt + N);                 // 2048
    float*  WVT   = WST + 2048;                        // 2048

    const int tb = 256;
    int prepTot = N * 32 + N + 2048;
    int ebk = (E / 4 + tb) / tb;
    prep_kernel<<<(prepTot + tb - 1) / tb, tb, 0, stream>>>(feat, pos, Ws, Wv, tpw,
                                                            featH, pos4, cnt, WST, WVT, N);
    scatter_kernel<<<ebk, tb, 0, stream>>>(esrc, edst, cnt, csrP, E);
    node_kernel<<<(N + 3) / 4, 256, 0, stream>>>(featH, pos4, csrP, cnt, WST, WVT, out, N);
}

// Round 11
// 189.917 us; speedup vs baseline: 1.0574x; 1.0343x over previous
//
#include <hip/hip_runtime.h>
#include <hip/hip_fp16.h>

#define SQRT3 1.7320508075688772f
#define INV_SQRT3 0.5773502691896258f
#define CAP 64
#define CHUNK 8

#define WAVE_SYNC() do { asm volatile("s_waitcnt lgkmcnt(0)" ::: "memory"); \
                         __builtin_amdgcn_wave_barrier(); } while (0)

// async DMA: lane L fetches 4B from its own global addr into lds_base + L*4
#define GLOAD_LDS4(GP, LP) __builtin_amdgcn_global_load_lds( \
    (const __attribute__((address_space(1))) void*)(GP), \
    (__attribute__((address_space(3))) void*)(LP), 4, 0, 0)

// ---------------- fused prep: featH(f16) + pos4 + folded TRANSPOSED weights + cnt=0 ----
// featH[node*32+cl] = half4{s_cl, v_cl0, v_cl1, v_cl2}  (256 B per node, contiguous)
// WST[j*64+u]: u<32 -> 0.125*w0[u]*Ws[u][j]; u>=32 -> 0.125*w3[u']*inv_sqrt3*Ws[u][j]
// WVT[o*64+u]: u<32 -> 0.125*w1[u]*Wv[u][o]; u>=32 -> 0.125*w2[u']*Wv[u][o]
__global__ void prep_kernel(const float* __restrict__ feat, const float* __restrict__ pos,
                            const float* __restrict__ Ws, const float* __restrict__ Wv,
                            const float* __restrict__ tpw,
                            uint2* __restrict__ featH, float4* __restrict__ pos4,
                            int* __restrict__ cnt,
                            float* __restrict__ WST, float* __restrict__ WVT, int N) {
    int i = blockIdx.x * blockDim.x + threadIdx.x;
    int totalF = N * 32;
    if (i < totalF) {
        int node = i >> 5, cl = i & 31;
        const float* fb = feat + (size_t)node * 128;
        float s  = fb[cl];
        float v0 = fb[32 + 3 * cl], v1 = fb[33 + 3 * cl], v2 = fb[34 + 3 * cl];
        __half2 h0 = __floats2half2_rn(s, v0);
        __half2 h1 = __floats2half2_rn(v1, v2);
        uint2 r;
        r.x = *(const unsigned int*)&h0;
        r.y = *(const unsigned int*)&h1;
        featH[i] = r;
        return;
    }
    int j = i - totalF;
    if (j < N) {
        pos4[j] = make_float4(pos[3 * j], pos[3 * j + 1], pos[3 * j + 2], 0.f);
        cnt[j] = 0;                        // zero scatter cursors (no memset pass)
        return;
    }
    int k = j - N;
    if (k < 2048) {
        int u = k >> 5, c = k & 31;        // c = output column (j for s-path, o for v-path)
        float ws = Ws[k], wv = Wv[k];
        float fs, fv;
        if (u < 32) {
            fs = 0.125f * tpw[u] * ws;
            fv = 0.125f * tpw[32 + u] * wv;
        } else {
            int uu = u - 32;
            fs = 0.125f * tpw[96 + uu] * INV_SQRT3 * ws;
            fv = 0.125f * tpw[64 + uu] * wv;
        }
        WST[c * 64 + u] = fs;
        WVT[c * 64 + u] = fv;
    }
}

// ---------------- single-pass padded-CSR scatter (proven R7) ----------------
__global__ void scatter_kernel(const int* __restrict__ esrc, const int* __restrict__ edst,
                               int* __restrict__ cnt, int* __restrict__ csrP, int E) {
    int t = blockIdx.x * blockDim.x + threadIdx.x;
    int e0 = t * 4;
    if (e0 + 4 <= E) {
        int4 s4 = *(const int4*)(esrc + e0);
        int4 d4 = *(const int4*)(edst + e0);
        int p;
        p = atomicAdd(&cnt[d4.x], 1); if (p < CAP) csrP[(size_t)d4.x * CAP + p] = s4.x;
        p = atomicAdd(&cnt[d4.y], 1); if (p < CAP) csrP[(size_t)d4.y * CAP + p] = s4.y;
        p = atomicAdd(&cnt[d4.z], 1); if (p < CAP) csrP[(size_t)d4.z * CAP + p] = s4.z;
        p = atomicAdd(&cnt[d4.w], 1); if (p < CAP) csrP[(size_t)d4.w * CAP + p] = s4.w;
    } else {
        for (int e = e0; e < E; ++e) {
            int d = edst[e];
            int p = atomicAdd(&cnt[d], 1);
            if (p < CAP) csrP[(size_t)d * CAP + p] = esrc[e];
        }
    }
}

// ---------------- per-node gather + TP + linear (DMA-staged, drain-only waits) ----
// 1 wave/node. Edge loop in CHUNK=8 blocks, double-buffered with ONLY vmcnt(0)/
// lgkmcnt(0) drains (the proven "minimum 2-phase" pattern):
//   prologue: issue chunk0; vmcnt(0)
//   loop c:   issue chunk c+1 (other buf) ; consume chunk c ; lgkmcnt(0) ; vmcnt(0)
// Land latency of c+1 overlaps consume of c; buffer reuse guarded by lgkm drain.

__global__ __launch_bounds__(256) void node_kernel(
    const uint2* __restrict__ featH, const float4* __restrict__ pos4,
    const int* __restrict__ csrP, const int* __restrict__ cnt,
    const float* __restrict__ WST, const float* __restrict__ WVT,
    float* __restrict__ out, int N)
{
    __shared__ uint2  stage[4][2][CHUNK][32];   // 16 KB staged featH blocks
    __shared__ int    csrL[4][64];
    __shared__ float4 geom[4][64];
    __shared__ float  sS[4][68], sX[4][68], sY[4][68], sZ[4][68];
    int lane = threadIdx.x & 63;
    int w    = threadIdx.x >> 6;
    int node = blockIdx.x * 4 + w;
    if (node >= N) return;                 // whole-wave exit; no block barriers used

    int deg = cnt[node];                   // cursor after scatter == degree
    int len = deg < CAP ? deg : CAP;
    int half = lane >> 5;
    int cl   = lane & 31;

    float4 pd = pos4[node];                // wave-uniform

    if (lane < len) {
        int s = csrP[(size_t)node * CAP + lane];
        csrL[w][lane] = s;
        float4 ps = pos4[s];
        float ex = pd.x - ps.x, ey = pd.y - ps.y, ez = pd.z - ps.z;
        float rr = SQRT3 * rsqrtf(ex * ex + ey * ey + ez * ez + 1e-12f);
        geom[w][lane] = make_float4(rr * ex, rr * ey, rr * ez, 0.f);
    }
    WAVE_SYNC();

    float A0 = 0.f, A1x = 0.f, A1y = 0.f, A1z = 0.f;   // s-channel cl: a0, a1
    float V0 = 0.f, V1 = 0.f, V2 = 0.f, T3 = 0.f;      // v-channel cl: a2, a3(raw)

    if (len > 0) {
        const char* fbase = (const char*)featH;
        // issue DMA loads for edges [c*CHUNK, min(len,(c+1)*CHUNK)) — uniform skip
        auto issue = [&](int c, int buf) {
            #pragma unroll
            for (int q = 0; q < CHUNK; ++q) {
                int e = c * CHUNK + q;
                if (e < len) {                              // wave-uniform branch
                    int si = csrL[w][e];                    // LDS broadcast (uniform)
                    const char* gp = fbase + ((size_t)(unsigned)si << 8) + (lane << 2);
                    GLOAD_LDS4(gp, &stage[w][buf][q][0]);
                }
            }
        };
        int nch = (len + CHUNK - 1) / CHUNK;
        issue(0, 0);
        asm volatile("s_waitcnt vmcnt(0)" ::: "memory");   // chunk 0 landed
        __builtin_amdgcn_sched_barrier(0);
        for (int c = 0; c < nch; ++c) {
            int buf = c & 1;
            if (c + 1 < nch) issue(c + 1, buf ^ 1);        // overlaps consume below
            #pragma unroll
            for (int j = 0; j < CHUNK / 2; ++j) {
                int e = c * CHUNK + 2 * j + half;          // <= 63 always
                uint2 fr = stage[w][buf][2 * j + half][cl];
                float4 g = geom[w][e];
                if (e < len) {
                    float2 lo = __half22float2(*(const __half2*)&fr.x);   // {s, v0}
                    float2 hi = __half22float2(*(const __half2*)&fr.y);   // {v1, v2}
                    A0 += lo.x;
                    A1x = fmaf(lo.x, g.x, A1x); A1y = fmaf(lo.x, g.y, A1y); A1z = fmaf(lo.x, g.z, A1z);
                    V0 += lo.y; V1 += hi.x; V2 += hi.y;
                    T3 = fmaf(lo.y, g.x, fmaf(hi.x, g.y, fmaf(hi.y, g.z, T3)));
                }
            }
            asm volatile("s_waitcnt lgkmcnt(0)" ::: "memory");  // stage reads done (buf reuse safe)
            __builtin_amdgcn_sched_barrier(0);
            asm volatile("s_waitcnt vmcnt(0)" ::: "memory");    // chunk c+1 fully landed
            __builtin_amdgcn_sched_barrier(0);
        }
    }

    // cross-half reduce (lanes L, L+32 hold same channel over disjoint edges)
    A0 += __shfl_xor(A0, 32);  A1x += __shfl_xor(A1x, 32);
    A1y += __shfl_xor(A1y, 32); A1z += __shfl_xor(A1z, 32);
    V0 += __shfl_xor(V0, 32);  V1 += __shfl_xor(V1, 32);
    V2 += __shfl_xor(V2, 32);  T3 += __shfl_xor(T3, 32);

    // SoA aggregate: [0,32)=s-path raw {A0 | A1x/y/z}, [32,64)=v-path raw {T3 | V0/1/2}
    int k = half ? (32 + cl) : cl;
    sS[w][k] = half ? T3 : A0;
    sX[w][k] = half ? V0 : A1x;
    sY[w][k] = half ? V1 : A1y;
    sZ[w][k] = half ? V2 : A1z;
    WAVE_SYNC();

    // epilogue: outputs j = lane, lane+64; contiguous transposed weight rows (float4)
    size_t ob = (size_t)node * 128;
    #pragma unroll
    for (int t = 0; t < 2; ++t) {
        int j = lane + 64 * t;
        const float *ap, *wp;
        if (j < 32) {
            ap = sS[w]; wp = WST + j * 64;
        } else {
            int v = j - 32;
            int o = v / 3, mm = v - 3 * o;
            ap = (mm == 0) ? sX[w] : (mm == 1) ? sY[w] : sZ[w];
            wp = WVT + o * 64;
        }
        float r = 0.f;
        #pragma unroll
        for (int q = 0; q < 16; ++q) {
            float4 a = *(const float4*)(ap + 4 * q);
            float4 b = *(const float4*)(wp + 4 * q);
            r = fmaf(a.x, b.x, r); r = fmaf(a.y, b.y, r);
            r = fmaf(a.z, b.z, r); r = fmaf(a.w, b.w, r);
        }
        out[ob + j] = r;                   // all scales folded into WST/WVT
    }
}

extern "C" void kernel_launch(void* const* d_in, const int* in_sizes, int n_in,
                              void* d_out, int out_size, void* d_ws, size_t ws_size,
                              hipStream_t stream) {
    const float* feat = (const float*)d_in[0];
    const float* pos  = (const float*)d_in[1];
    const int*   esrc = (const int*)d_in[2];
    const int*   edst = (const int*)d_in[3];
    const float* tpw  = (const float*)d_in[4];
    const float* Ws   = (const float*)d_in[5];
    const float* Wv   = (const float*)d_in[6];
    float* out = (float*)d_out;

    int N = in_sizes[0] / 128;
    int E = in_sizes[2];

    uint2*  featH = (uint2*)d_ws;                      // N*32   (12.8 MB, 256 B/node)
    float4* pos4  = (float4*)(featH + (size_t)N * 32); // N      (0.8 MB)
    int*    csrP  = (int*)(pos4 + N);                  // N*CAP  (12.8 MB)
    int*    cnt   = csrP + (size_t)N * CAP;            // N      (0.2 MB)
    float*  WST   = (float*)(cnt + N);                 // 2048
    float*  WVT   = WST + 2048;                        // 2048

    const int tb = 256;
    int prepTot = N * 32 + N + 2048;
    int ebk = (E / 4 + tb) / tb;
    prep_kernel<<<(prepTot + tb - 1) / tb, tb, 0, stream>>>(feat, pos, Ws, Wv, tpw,
                                                            featH, pos4, cnt, WST, WVT, N);
    scatter_kernel<<<ebk, tb, 0, stream>>>(esrc, edst, cnt, csrP, E);
    node_kernel<<<(N + 3) / 4, 256, 0, stream>>>(featH, pos4, csrP, cnt, WST, WVT, out, N);
}